// Round 12
// baseline (478.781 us; speedup 1.0000x reference)
//
#include <hip/hip_runtime.h>
#include <hip/hip_bf16.h>

#define HC    256
#define FIN   32
#define NH    8
#define GROUP 4     // dst nodes per block (agg)
#define CAP   128   // staged edges per chunk

typedef __hip_bfloat16 bf16;
typedef __attribute__((ext_vector_type(8))) short short8;
typedef __attribute__((ext_vector_type(4))) float floatx4;

__device__ __forceinline__ float blo(unsigned int u) { return __uint_as_float(u << 16); }
__device__ __forceinline__ float bhi(unsigned int u) { return __uint_as_float(u & 0xffff0000u); }
__device__ __forceinline__ unsigned short bf16bits(float v) {
  unsigned u = __float_as_uint(v);
  unsigned r = (u + 0x7FFFu + ((u >> 16) & 1u)) >> 16;   // RNE, matches __float2bfloat16
  return (unsigned short)r;
}
__device__ __forceinline__ float bf16tof(unsigned short u) {
  return __uint_as_float(((unsigned)u) << 16);
}

// ---------------- CSR build ---------------------------------------------------
__global__ void count_kernel(const int* __restrict__ dst, int* __restrict__ cnt, int E_) {
  int e = blockIdx.x * blockDim.x + threadIdx.x;
  if (e < E_) atomicAdd(&cnt[dst[e]], 1);
}

__global__ __launch_bounds__(256) void
scan_partial(const int* __restrict__ cnt, int* __restrict__ tmp,
             int* __restrict__ bsum, int N_) {
  __shared__ int part[256];
  int t = threadIdx.x, i = blockIdx.x * 256 + t;
  int v = (i < N_) ? cnt[i] : 0;
  part[t] = v;
  __syncthreads();
#pragma unroll
  for (int off = 1; off < 256; off <<= 1) {
    int u = (t >= off) ? part[t - off] : 0;
    __syncthreads();
    part[t] += u;
    __syncthreads();
  }
  if (i < N_) tmp[i] = part[t];
  if (t == 255) bsum[blockIdx.x] = part[255];
}

__global__ __launch_bounds__(1024) void
scan_bsum(int* __restrict__ bsum, int NB) {
  __shared__ int part[1024];
  int t = threadIdx.x;
  int v = (t < NB) ? bsum[t] : 0;
  part[t] = v;
  __syncthreads();
  for (int off = 1; off < 1024; off <<= 1) {
    int u = (t >= off) ? part[t - off] : 0;
    __syncthreads();
    part[t] += u;
    __syncthreads();
  }
  if (t < NB) bsum[t] = part[t] - v;
}

__global__ __launch_bounds__(256) void
scan_final(const int* __restrict__ cnt, const int* __restrict__ tmp,
           const int* __restrict__ bsum, int* __restrict__ rowptr,
           int* __restrict__ fill, int N_, int E_) {
  int t = threadIdx.x, i = blockIdx.x * 256 + t;
  if (i < N_) {
    int ex = bsum[blockIdx.x] + tmp[i] - cnt[i];
    rowptr[i] = ex;
    fill[i] = ex;
  }
  if (i == 0) rowptr[N_] = E_;
}

__global__ void scatter_kernel(const int* __restrict__ src, const int* __restrict__ dst,
                               int* __restrict__ fill, const float* __restrict__ edge_attr,
                               int* __restrict__ srcs, float* __restrict__ eattr_s, int E_) {
  int e = blockIdx.x * blockDim.x + threadIdx.x;
  if (e < E_) {
    int pos = atomicAdd(&fill[dst[e]], 1);
    srcs[pos] = src[e];
    const float4* ep = (const float4*)(edge_attr + (size_t)e * NH);
    float4 a0 = ep[0], a1 = ep[1];
    float4* op = (float4*)(eattr_s + (size_t)pos * NH);
    op[0] = a0; op[1] = a1;
  }
}

// ---- fold: M_l[8x8], P matrices, and MFMA B-fragment packs of W1/W2 ---------
// Mbuf floats: [0:64) M1 | [64:128) M2 | [128:384) P1s | [384:640) P1d
//              | [640:896) P2s | [896:1152) P2d
// Bp (ushort): layer l (0/1) at l*8192: [(h*2+nt)*64+lane]*8+j  = bf16(W[k][col])
__global__ void fold_kernel(const float* __restrict__ We1, const float* __restrict__ ae1,
                            const float* __restrict__ We2, const float* __restrict__ ae2,
                            const float* __restrict__ W1, const float* __restrict__ as1,
                            const float* __restrict__ ad1,
                            const float* __restrict__ W2, const float* __restrict__ as2,
                            const float* __restrict__ ad2,
                            float* __restrict__ M, unsigned short* __restrict__ Bp) {
  for (int idx = threadIdx.x; idx < 1152 + 16384; idx += 256) {
    if (idx < 1152) {
      const float* A; const float* V; int i;
      if (idx < 64)       { i = idx;       A = We1; V = ae1; }
      else if (idx < 128) { i = idx - 64;  A = We2; V = ae2; }
      else if (idx < 384) { i = idx - 128; A = W1;  V = as1; }
      else if (idx < 640) { i = idx - 384; A = W1;  V = ad1; }
      else if (idx < 896) { i = idx - 640; A = W2;  V = as2; }
      else                { i = idx - 896; A = W2;  V = ad2; }
      int k = i >> 3, h = i & 7;
      float s = 0.f;
      for (int c = 0; c < FIN; ++c)
        s = fmaf(A[k * HC + h * FIN + c], V[h * FIN + c], s);
      M[idx] = s;
    } else {
      int e = idx - 1152;
      int l = e >> 13, e2 = e & 8191;
      int h = e2 >> 10, nt = (e2 >> 9) & 1, lane = (e2 >> 3) & 63, j = e2 & 7;
      int k = (lane >> 4) * 8 + j;
      int col = h * 32 + nt * 16 + (lane & 15);
      const float* Wx = l ? W2 : W1;
      Bp[(size_t)l * 8192 + (size_t)((h * 2 + nt) * 64 + lane) * 8 + j] =
          bf16bits(Wx[k * HC + col]);
    }
  }
}

// ---- layer-1 prep: xq1 = bf16(emb[node_ids]); alsrc1/aldst1 = x @ P1 --------
__global__ __launch_bounds__(256) void
prep1_kernel(const float* __restrict__ emb, const int* __restrict__ node_ids,
             const float* __restrict__ P,
             unsigned short* __restrict__ xq, float* __restrict__ alsrc,
             float* __restrict__ aldst, int N_) {
  __shared__ float xs[8][33];
  int t = threadIdx.x, n0 = blockIdx.x * 8;
  int nl = t >> 5, c = t & 31;
  int n = n0 + nl;
  if (n < N_) {
    float v = emb[(size_t)node_ids[n] * FIN + c];
    xq[(size_t)n * FIN + c] = bf16bits(v);
    xs[nl][c] = v;
  }
  __syncthreads();
  if (t < 64) {
    int nl2 = t >> 3, h = t & 7;
    int n2 = n0 + nl2;
    if (n2 < N_) {
      float sa = 0.f, sd = 0.f;
#pragma unroll
      for (int k = 0; k < FIN; ++k) {
        float x = xs[nl2][k];
        sa = fmaf(x, P[k * 8 + h], sa);
        sd = fmaf(x, P[256 + k * 8 + h], sd);
      }
      alsrc[(size_t)n2 * NH + h] = sa;
      aldst[(size_t)n2 * NH + h] = sd;
    }
  }
}

// ---- prep2: alsrc2/aldst2 = bf16(x1) @ P2 (xq2 already written by epi1) -----
__global__ __launch_bounds__(256) void
prep2_kernel(const unsigned short* __restrict__ xq,
             const float* __restrict__ P,
             float* __restrict__ alsrc, float* __restrict__ aldst, int N_) {
  __shared__ float xs[8][33];
  int t = threadIdx.x, n0 = blockIdx.x * 8;
  int nl = t >> 5, c = t & 31;
  int n = n0 + nl;
  if (n < N_) xs[nl][c] = bf16tof(xq[(size_t)n * FIN + c]);
  __syncthreads();
  if (t < 64) {
    int nl2 = t >> 3, h = t & 7;
    int n2 = n0 + nl2;
    if (n2 < N_) {
      float sa = 0.f, sd = 0.f;
#pragma unroll
      for (int k = 0; k < FIN; ++k) {
        float x = xs[nl2][k];
        sa = fmaf(x, P[k * 8 + h], sa);
        sd = fmaf(x, P[256 + k * 8 + h], sd);
      }
      alsrc[(size_t)n2 * NH + h] = sa;
      aldst[(size_t)n2 * NH + h] = sd;
    }
  }
}

// ---- agg: softmax-weighted gather -> z (bf16, global). Epilogue moved out. --
__global__ __launch_bounds__(256) void
agg_kernel(const int* __restrict__ rowptr, const int* __restrict__ srcs,
           const float* __restrict__ eattr, const float* __restrict__ Mg,
           const float* __restrict__ alsrc, const float* __restrict__ aldst,
           const unsigned short* __restrict__ xq,
           unsigned int* __restrict__ Zg,     // [N*64] uint2-packed bf16 (as uint pairs)
           int N_) {
  __shared__ __align__(16) char smem[17920];
  unsigned int* xsu = (unsigned int*)smem;        // [CAP*16] packed bf16 (8 KB)
  float* wsf    = (float*)(smem + 8192);          // [CAP][8] (4 KB)
  float4* red4  = (float4*)smem;                  // [1024] combine pool (16 KB)
  float* Ms     = (float*)(smem + 16384);         // 64
  float* ald_s  = (float*)(smem + 16640);         // 32
  float* denred = (float*)(smem + 16768);         // [4][4][8]
  float* den_s  = (float*)(smem + 17280);         // [4][8]

  int t = threadIdx.x;
  int n0 = blockIdx.x * GROUP;
  int slot = t >> 6, l = t & 63, h = l >> 3, q = l & 7;

  int rp[GROUP + 1];
#pragma unroll
  for (int i = 0; i <= GROUP; ++i) {
    int nn = n0 + i;
    rp[i] = rowptr[(nn <= N_) ? nn : N_];
  }
  if (t < 64) Ms[t] = Mg[t];
  if (t < GROUP * NH) {
    int nn = n0 + (t >> 3);
    ald_s[t] = (nn < N_) ? aldst[(size_t)nn * NH + (t & 7)] : 0.f;
  }
  __syncthreads();

  float4 acc[GROUP];
  float dn[GROUP];
#pragma unroll
  for (int i = 0; i < GROUP; ++i) { acc[i] = make_float4(0.f, 0.f, 0.f, 0.f); dn[i] = 0.f; }

  int beg = rp[0], end = rp[GROUP];
  for (int cbeg = beg; cbeg < end; cbeg += CAP) {
    int clen = end - cbeg; if (clen > CAP) clen = CAP;

    int ntask = clen * 8;
    for (int idx = t; idx < ntask; idx += 256) {
      int e = idx >> 3, c4 = idx & 7;
      int s = srcs[cbeg + e];
      uint2 v = *(const uint2*)(xq + (size_t)s * FIN + c4 * 4);
      *(uint2*)&xsu[e * 16 + c4 * 2] = v;
    }
    {
      int e2 = t >> 1, half = t & 1;
      if (e2 < clen) {
        int j = cbeg + e2;
        int ii = 0;
        while (j >= rp[ii + 1]) ++ii;
        int sn = srcs[j];
        float4 eah = *(const float4*)(eattr + (size_t)j * NH + half * 4);
        float4 ash = *(const float4*)(alsrc + (size_t)sn * NH + half * 4);
        float eaf[4] = {eah.x, eah.y, eah.z, eah.w};
        float ea[8];
#pragma unroll
        for (int c = 0; c < 4; ++c) {
          float other = __shfl_xor(eaf[c], 1, 64);
          ea[half * 4 + c] = eaf[c];
          ea[(1 - half) * 4 + c] = other;
        }
        float asf[4] = {ash.x, ash.y, ash.z, ash.w};
        float o[4];
#pragma unroll
        for (int i4 = 0; i4 < 4; ++i4) {
          int hh = half * 4 + i4;
          float al = 0.f;
#pragma unroll
          for (int kk = 0; kk < NH; ++kk) al = fmaf(ea[kk], Ms[kk * NH + hh], al);
          float a = asf[i4] + ald_s[ii * NH + hh] + al;
          a = (a >= 0.f) ? a : 0.2f * a;
          o[i4] = __expf(a);
        }
        *(float4*)&wsf[e2 * 8 + half * 4] = make_float4(o[0], o[1], o[2], o[3]);
      }
    }
    __syncthreads();
#pragma unroll
    for (int i = 0; i < GROUP; ++i) {
      int lo = rp[i] > cbeg ? rp[i] - cbeg : 0;
      int hi = rp[i + 1] - cbeg; if (hi > clen) hi = clen;
      float4 a = acc[i];
      float d = dn[i];
#pragma unroll 2
      for (int le = lo + slot; le < hi; le += 4) {
        float w = wsf[le * 8 + h];
        uint2 u = *(const uint2*)&xsu[le * 16 + q * 2];
        a.x = fmaf(blo(u.x), w, a.x);
        a.y = fmaf(bhi(u.x), w, a.y);
        a.z = fmaf(blo(u.y), w, a.z);
        a.w = fmaf(bhi(u.y), w, a.w);
        d += w;
      }
      acc[i] = a; dn[i] = d;
    }
    __syncthreads();
  }

  if (q == 0) {
#pragma unroll
    for (int i = 0; i < GROUP; ++i) denred[slot * 32 + i * 8 + h] = dn[i];
  }
#pragma unroll
  for (int i = 0; i < GROUP; ++i) red4[i * 256 + t] = acc[i];
  __syncthreads();

  if (t < 32) {
    int i = t >> 3, hh = t & 7;
    float d = denred[i * 8 + hh] + denred[32 + i * 8 + hh] +
              denred[64 + i * 8 + hh] + denred[96 + i * 8 + hh];
    den_s[t] = 1.0f / (d + 1e-16f);
  }
  int i2 = t >> 6, l2 = t & 63;
  float4 r0 = red4[i2 * 256 + l2];
  float4 r1 = red4[i2 * 256 + 64 + l2];
  float4 r2 = red4[i2 * 256 + 128 + l2];
  float4 r3 = red4[i2 * 256 + 192 + l2];
  __syncthreads();
  float rden = den_s[i2 * 8 + (l2 >> 3)];
  float zx = (r0.x + r1.x + r2.x + r3.x) * rden;
  float zy = (r0.y + r1.y + r2.y + r3.y) * rden;
  float zz = (r0.z + r1.z + r2.z + r3.z) * rden;
  float zw = (r0.w + r1.w + r2.w + r3.w) * rden;
  int nn = n0 + i2;
  if (nn < N_) {
    unsigned int lo = (unsigned)bf16bits(zx) | ((unsigned)bf16bits(zy) << 16);
    unsigned int hi = (unsigned)bf16bits(zz) | ((unsigned)bf16bits(zw) << 16);
    uint2* zp = (uint2*)Zg;
    zp[(size_t)nn * 64 + l2] = make_uint2(lo, hi);
  }
}

// ---- epi: G = relu(Z @ W_blockdiag + b) via MFMA; x' = G @ Wlin + blin ------
// 64-row tile, 4 waves x 16 rows. A-frag: A[m=lane&15][k=quad*8+j] (zl LDS,
// row stride 264 bf16). D: row=(quad)*4+reg, col=lane&15. G -> LDS col-major
// [256][68] bf16, then VALU lin with broadcast reads.
template <int K2, bool LOGITS>
__global__ __launch_bounds__(256) void
epi_kernel(const unsigned int* __restrict__ Zg, const unsigned short* __restrict__ Bp,
           const float* __restrict__ bvec, const float* __restrict__ Wlin,
           const float* __restrict__ blin,
           unsigned short* __restrict__ xqn,   // LOGITS: bf16 [N,32]
           float* __restrict__ xoutf,          // !LOGITS: f32 [N,K2]
           int N_) {
  __shared__ __align__(16) unsigned short pool[256 * 68];  // 34.8 KB
  int t = threadIdx.x;
  int r0 = blockIdx.x * 64;

  // stage Z tile: 64 rows x 256 ch bf16, LDS row stride 264
  for (int idx = t; idx < 64 * 32; idx += 256) {
    int row = idx >> 5, seg = idx & 31;
    uint4 v = (r0 + row < N_) ? ((const uint4*)Zg)[(size_t)(r0 + row) * 16 + seg >> 1]
                              : make_uint4(0u, 0u, 0u, 0u);
    // note: Zg is uint2-packed; read as uint4 over pairs -> recompute index:
    (void)v;
  }
  // (replaced below with a correct uint2-based stager)
  __syncthreads();
  for (int idx = t; idx < 64 * 64; idx += 256) {
    int row = idx >> 6, seg = idx & 63;                 // seg: 4-ch uint2
    uint2 v = (r0 + row < N_) ? ((const uint2*)Zg)[(size_t)(r0 + row) * 64 + seg]
                              : make_uint2(0u, 0u);
    *(uint2*)&pool[row * 264 + seg * 4] = v;
  }
  __syncthreads();

  int w = t >> 6, lane = t & 63;
  int quad = lane >> 4, n15 = lane & 15;

  const short8* bp = (const short8*)Bp;
  floatx4 acc0[8], acc1[8];
#pragma unroll
  for (int h = 0; h < 8; ++h) {
    floatx4 zinit = {0.f, 0.f, 0.f, 0.f};
    short8 a = *(const short8*)&pool[(w * 16 + n15) * 264 + h * 32 + quad * 8];
    short8 b0 = bp[(h * 2 + 0) * 64 + lane];
    short8 b1 = bp[(h * 2 + 1) * 64 + lane];
    acc0[h] = __builtin_amdgcn_mfma_f32_16x16x32_bf16(a, b0, zinit, 0, 0, 0);
    acc1[h] = __builtin_amdgcn_mfma_f32_16x16x32_bf16(a, b1, zinit, 0, 0, 0);
  }
  __syncthreads();   // zl reads done; pool becomes G (col-major, stride 68)

#pragma unroll
  for (int h = 0; h < 8; ++h) {
#pragma unroll
    for (int nt = 0; nt < 2; ++nt) {
      floatx4 acc = nt ? acc1[h] : acc0[h];
      int col = h * 32 + nt * 16 + n15;
      float bb = bvec[col];
      unsigned short gq[4];
#pragma unroll
      for (int r = 0; r < 4; ++r) {
        float v = acc[r] + bb;
        gq[r] = bf16bits(v > 0.f ? v : 0.f);
      }
      *(ushort4*)&pool[col * 68 + w * 16 + quad * 4] =
          make_ushort4(gq[0], gq[1], gq[2], gq[3]);
    }
  }
  __syncthreads();

  // lin: out[row][c] = sum_col G[col][row] * Wlin[col][c] + blin[c]
  {
    const int PER = K2 / 4;
    int row = t >> 2, sub = t & 3;
    float acc[PER];
#pragma unroll
    for (int i = 0; i < PER; ++i) acc[i] = blin[sub * PER + i];
    for (int col = 0; col < 256; ++col) {
      float gv = bf16tof(pool[col * 68 + row]);
      const float* wl = &Wlin[col * K2 + sub * PER];
#pragma unroll
      for (int i = 0; i < PER; ++i) acc[i] = fmaf(gv, wl[i], acc[i]);
    }
    int grow = r0 + row;
    if (grow < N_) {
      if (LOGITS) {
        unsigned short ov[8];
#pragma unroll
        for (int i = 0; i < PER; ++i) ov[i] = bf16bits(acc[i]);
        *(uint4*)&xqn[(size_t)grow * 32 + sub * 8] = *(uint4*)ov;
      } else {
#pragma unroll
        for (int i = 0; i < PER; ++i)
          xoutf[(size_t)grow * K2 + sub * PER + i] = acc[i];
      }
    }
  }
}

// ---------------- classifier: sigmoid(sum(fu*fm)) ----------------------------
__global__ void clf_kernel(const int* __restrict__ eli, const float* __restrict__ ela,
                           const float* __restrict__ x2, const float* __restrict__ clfW,
                           const float* __restrict__ clfb, float* __restrict__ out, int L_) {
  int i = blockIdx.x * blockDim.x + threadIdx.x;
  if (i >= L_) return;
  int u = eli[i], m = eli[L_ + i];
  const float4* xup = (const float4*)(x2 + (size_t)u * NH);
  const float4* xmp = (const float4*)(x2 + (size_t)m * NH);
  const float4* eap = (const float4*)(ela + (size_t)i * NH);
  float4 xu0 = xup[0], xu1 = xup[1];
  float4 xm0 = xmp[0], xm1 = xmp[1];
  float4 el0 = eap[0], el1 = eap[1];
  float xu[NH] = {xu0.x, xu0.y, xu0.z, xu0.w, xu1.x, xu1.y, xu1.z, xu1.w};
  float xm[NH] = {xm0.x, xm0.y, xm0.z, xm0.w, xm1.x, xm1.y, xm1.z, xm1.w};
  float el[NH] = {el0.x, el0.y, el0.z, el0.w, el1.x, el1.y, el1.z, el1.w};
  float fu[NH];
#pragma unroll
  for (int kk = 0; kk < NH; ++kk) fu[kk] = clfb[kk];
#pragma unroll
  for (int j = 0; j < NH; ++j) {
#pragma unroll
    for (int kk = 0; kk < NH; ++kk) fu[kk] = fmaf(xu[j], clfW[j * NH + kk], fu[kk]);
  }
#pragma unroll
  for (int j = 0; j < NH; ++j) {
#pragma unroll
    for (int kk = 0; kk < NH; ++kk) fu[kk] = fmaf(el[j], clfW[(NH + j) * NH + kk], fu[kk]);
  }
  float dot = 0.f;
#pragma unroll
  for (int kk = 0; kk < NH; ++kk) dot += fu[kk] * xm[kk];
  out[i] = 1.f / (1.f + expf(-dot));
}

extern "C" void kernel_launch(void* const* d_in, const int* in_sizes, int n_in,
                              void* d_out, int out_size, void* d_ws, size_t ws_size,
                              hipStream_t stream) {
  const int* node_ids   = (const int*)d_in[0];
  const int* edge_index = (const int*)d_in[1];
  const int* eli        = (const int*)d_in[2];
  const float* edge_attr = (const float*)d_in[4];
  const float* ela       = (const float*)d_in[5];
  const float* emb       = (const float*)d_in[6];
  const float* W1     = (const float*)d_in[7];
  const float* a_src1 = (const float*)d_in[8];
  const float* a_dst1 = (const float*)d_in[9];
  const float* We1    = (const float*)d_in[10];
  const float* a_e1   = (const float*)d_in[11];
  const float* b1     = (const float*)d_in[12];
  const float* lin1W  = (const float*)d_in[13];
  const float* lin1b  = (const float*)d_in[14];
  const float* W2     = (const float*)d_in[15];
  const float* a_src2 = (const float*)d_in[16];
  const float* a_dst2 = (const float*)d_in[17];
  const float* We2    = (const float*)d_in[18];
  const float* a_e2   = (const float*)d_in[19];
  const float* b2     = (const float*)d_in[20];
  const float* lin5W  = (const float*)d_in[21];
  const float* lin5b  = (const float*)d_in[22];
  const float* clfW   = (const float*)d_in[23];
  const float* clfb   = (const float*)d_in[24];

  const int N_ = in_sizes[0];
  const int E_ = in_sizes[1] / 2;
  const int L_ = in_sizes[2] / 2;
  const int* src  = edge_index;
  const int* dstp = edge_index + E_;

  char* p = (char*)d_ws;
  auto carve = [&](size_t bytes) -> char* {
    char* r = p;
    p += (bytes + 255) & ~(size_t)255;
    return r;
  };
  unsigned short* xq1  = (unsigned short*)carve((size_t)N_ * FIN * 2);
  unsigned short* xq2  = (unsigned short*)carve((size_t)N_ * FIN * 2);
  unsigned int* Zbuf   = (unsigned int*)carve((size_t)N_ * HC * 2);   // bf16 z, 25.6 MB
  float* eattr_s = (float*)carve((size_t)E_ * NH * 4);                // 25.6 MB
  float* alsrc1  = (float*)carve((size_t)N_ * NH * 4);
  float* aldst1  = (float*)carve((size_t)N_ * NH * 4);
  float* alsrc2  = (float*)carve((size_t)N_ * NH * 4);
  float* aldst2  = (float*)carve((size_t)N_ * NH * 4);
  float* x2b     = (float*)carve((size_t)N_ * NH * 4);
  float* Mbuf    = (float*)carve(1152 * 4);
  unsigned short* Bp = (unsigned short*)carve(16384 * 2);
  int*   cnt     = (int*)carve((size_t)N_ * 4);
  int*   rowptr  = (int*)carve((size_t)(N_ + 1) * 4);
  int*   fill    = (int*)carve((size_t)N_ * 4);
  int*   stmp    = (int*)carve((size_t)N_ * 4);
  int*   bsum    = (int*)carve(1024 * 4);
  int*   srcs    = (int*)carve((size_t)E_ * 4);

  hipMemsetAsync(cnt, 0, (size_t)N_ * 4, stream);
  int eb = (E_ + 255) / 256;
  int nb = (N_ + 255) / 256;
  fold_kernel<<<1, 256, 0, stream>>>(We1, a_e1, We2, a_e2, W1, a_src1, a_dst1,
                                     W2, a_src2, a_dst2, Mbuf, Bp);
  count_kernel<<<eb, 256, 0, stream>>>(dstp, cnt, E_);
  scan_partial<<<nb, 256, 0, stream>>>(cnt, stmp, bsum, N_);
  scan_bsum<<<1, 1024, 0, stream>>>(bsum, nb);
  scan_final<<<nb, 256, 0, stream>>>(cnt, stmp, bsum, rowptr, fill, N_, E_);
  scatter_kernel<<<eb, 256, 0, stream>>>(src, dstp, fill, edge_attr, srcs, eattr_s, E_);
  prep1_kernel<<<(N_ + 7) / 8, 256, 0, stream>>>(emb, node_ids, Mbuf + 128,
                                                 xq1, alsrc1, aldst1, N_);

  int gb = (N_ + GROUP - 1) / GROUP;
  int ebk = (N_ + 63) / 64;
  // ---- layer 1 ----
  agg_kernel<<<gb, 256, 0, stream>>>(rowptr, srcs, eattr_s, Mbuf, alsrc1, aldst1,
                                     xq1, Zbuf, N_);
  epi_kernel<32, true><<<ebk, 256, 0, stream>>>(Zbuf, Bp, b1, lin1W, lin1b,
                                                xq2, nullptr, N_);
  prep2_kernel<<<(N_ + 7) / 8, 256, 0, stream>>>(xq2, Mbuf + 640, alsrc2, aldst2, N_);

  // ---- layer 2 ----
  agg_kernel<<<gb, 256, 0, stream>>>(rowptr, srcs, eattr_s, Mbuf + 64, alsrc2, aldst2,
                                     xq2, Zbuf, N_);
  epi_kernel<8, false><<<ebk, 256, 0, stream>>>(Zbuf, Bp + 8192, b2, lin5W, lin5b,
                                                nullptr, x2b, N_);

  // ---- classifier ----
  clf_kernel<<<(L_ + 255) / 256, 256, 0, stream>>>(eli, ela, x2b, clfW, clfb,
                                                   (float*)d_out, L_);
}

// Round 13
// 426.164 us; speedup vs baseline: 1.1235x; 1.1235x over previous
//
#include <hip/hip_runtime.h>
#include <hip/hip_bf16.h>

#define HC    256
#define FIN   32
#define NH    8
#define GROUP 4     // dst nodes per block (agg)
#define CAP   128   // staged edges per chunk

typedef __hip_bfloat16 bf16;
typedef __attribute__((ext_vector_type(8))) short short8;
typedef __attribute__((ext_vector_type(4))) float floatx4;

__device__ __forceinline__ float blo(unsigned int u) { return __uint_as_float(u << 16); }
__device__ __forceinline__ float bhi(unsigned int u) { return __uint_as_float(u & 0xffff0000u); }
__device__ __forceinline__ unsigned short bf16bits(float v) {
  unsigned u = __float_as_uint(v);
  unsigned r = (u + 0x7FFFu + ((u >> 16) & 1u)) >> 16;   // RNE
  return (unsigned short)r;
}
__device__ __forceinline__ float bf16tof(unsigned short u) {
  return __uint_as_float(((unsigned)u) << 16);
}

// ---------------- CSR build ---------------------------------------------------
__global__ void count_kernel(const int* __restrict__ dst, int* __restrict__ cnt, int E_) {
  int e = blockIdx.x * blockDim.x + threadIdx.x;
  if (e < E_) atomicAdd(&cnt[dst[e]], 1);
}

__global__ __launch_bounds__(256) void
scan_partial(const int* __restrict__ cnt, int* __restrict__ tmp,
             int* __restrict__ bsum, int N_) {
  __shared__ int part[256];
  int t = threadIdx.x, i = blockIdx.x * 256 + t;
  int v = (i < N_) ? cnt[i] : 0;
  part[t] = v;
  __syncthreads();
#pragma unroll
  for (int off = 1; off < 256; off <<= 1) {
    int u = (t >= off) ? part[t - off] : 0;
    __syncthreads();
    part[t] += u;
    __syncthreads();
  }
  if (i < N_) tmp[i] = part[t];
  if (t == 255) bsum[blockIdx.x] = part[255];
}

__global__ __launch_bounds__(1024) void
scan_bsum(int* __restrict__ bsum, int NB) {
  __shared__ int part[1024];
  int t = threadIdx.x;
  int v = (t < NB) ? bsum[t] : 0;
  part[t] = v;
  __syncthreads();
  for (int off = 1; off < 1024; off <<= 1) {
    int u = (t >= off) ? part[t - off] : 0;
    __syncthreads();
    part[t] += u;
    __syncthreads();
  }
  if (t < NB) bsum[t] = part[t] - v;
}

__global__ __launch_bounds__(256) void
scan_final(const int* __restrict__ cnt, const int* __restrict__ tmp,
           const int* __restrict__ bsum, int* __restrict__ rowptr,
           int* __restrict__ fill, int N_, int E_) {
  int t = threadIdx.x, i = blockIdx.x * 256 + t;
  if (i < N_) {
    int ex = bsum[blockIdx.x] + tmp[i] - cnt[i];
    rowptr[i] = ex;
    fill[i] = ex;
  }
  if (i == 0) rowptr[N_] = E_;
}

__global__ void scatter_kernel(const int* __restrict__ src, const int* __restrict__ dst,
                               int* __restrict__ fill, const float* __restrict__ edge_attr,
                               int* __restrict__ srcs, float* __restrict__ eattr_s, int E_) {
  int e = blockIdx.x * blockDim.x + threadIdx.x;
  if (e < E_) {
    int pos = atomicAdd(&fill[dst[e]], 1);
    srcs[pos] = src[e];
    const float4* ep = (const float4*)(edge_attr + (size_t)e * NH);
    float4 a0 = ep[0], a1 = ep[1];
    float4* op = (float4*)(eattr_s + (size_t)pos * NH);
    op[0] = a0; op[1] = a1;
  }
}

// ---- fold: M/P matrices + MFMA B-fragment packs of W1/W2 AND lin1W/lin5W ----
// Mbuf floats: [0:64) M1 | [64:128) M2 | [128:384) P1s | [384:640) P1d
//              | [640:896) P2s | [896:1152) P2d
// Bp ushorts:  [0:8192) W1-pack | [8192:16384) W2-pack
//              | [16384:24576) lin1W-pack (16 tiles = kt*2+ct)
//              | [24576:28672) lin5W-pack (8 tiles = kt, cols>=8 zero)
__global__ void fold_kernel(const float* __restrict__ We1, const float* __restrict__ ae1,
                            const float* __restrict__ We2, const float* __restrict__ ae2,
                            const float* __restrict__ W1, const float* __restrict__ as1,
                            const float* __restrict__ ad1,
                            const float* __restrict__ W2, const float* __restrict__ as2,
                            const float* __restrict__ ad2,
                            const float* __restrict__ lin1W, const float* __restrict__ lin5W,
                            float* __restrict__ M, unsigned short* __restrict__ Bp) {
  for (int idx = threadIdx.x; idx < 1152 + 16384 + 12288; idx += 256) {
    if (idx < 1152) {
      const float* A; const float* V; int i;
      if (idx < 64)       { i = idx;       A = We1; V = ae1; }
      else if (idx < 128) { i = idx - 64;  A = We2; V = ae2; }
      else if (idx < 384) { i = idx - 128; A = W1;  V = as1; }
      else if (idx < 640) { i = idx - 384; A = W1;  V = ad1; }
      else if (idx < 896) { i = idx - 640; A = W2;  V = as2; }
      else                { i = idx - 896; A = W2;  V = ad2; }
      int k = i >> 3, h = i & 7;
      float s = 0.f;
      for (int c = 0; c < FIN; ++c)
        s = fmaf(A[k * HC + h * FIN + c], V[h * FIN + c], s);
      M[idx] = s;
    } else if (idx < 17536) {
      int e = idx - 1152;
      int l = e >> 13, e2 = e & 8191;
      int h = e2 >> 10, nt = (e2 >> 9) & 1, lane = (e2 >> 3) & 63, j = e2 & 7;
      int k = (lane >> 4) * 8 + j;
      int col = h * 32 + nt * 16 + (lane & 15);
      const float* Wx = l ? W2 : W1;
      Bp[(size_t)l * 8192 + (size_t)((h * 2 + nt) * 64 + lane) * 8 + j] =
          bf16bits(Wx[k * HC + col]);
    } else if (idx < 25728) {
      int e = idx - 17536;               // lin1W pack: tile = kt*2+ct
      int tile = e >> 9, rem = e & 511, lane = rem >> 3, j = rem & 7;
      int kt = tile >> 1, ct = tile & 1;
      int k = kt * 32 + (lane >> 4) * 8 + j;
      int col = ct * 16 + (lane & 15);
      Bp[16384 + (size_t)tile * 512 + (size_t)lane * 8 + j] =
          bf16bits(lin1W[k * 32 + col]);
    } else {
      int e = idx - 25728;               // lin5W pack: tile = kt, pad cols >= 8
      int kt = e >> 9, rem = e & 511, lane = rem >> 3, j = rem & 7;
      int k = kt * 32 + (lane >> 4) * 8 + j;
      int n = lane & 15;
      Bp[24576 + (size_t)kt * 512 + (size_t)lane * 8 + j] =
          (n < 8) ? bf16bits(lin5W[k * 8 + n]) : (unsigned short)0;
    }
  }
}

// ---- layer-1 prep: xq1 = bf16(emb[node_ids]); alsrc1/aldst1 = x @ P1 --------
__global__ __launch_bounds__(256) void
prep1_kernel(const float* __restrict__ emb, const int* __restrict__ node_ids,
             const float* __restrict__ P,
             unsigned short* __restrict__ xq, float* __restrict__ alsrc,
             float* __restrict__ aldst, int N_) {
  __shared__ float xs[8][33];
  int t = threadIdx.x, n0 = blockIdx.x * 8;
  int nl = t >> 5, c = t & 31;
  int n = n0 + nl;
  if (n < N_) {
    float v = emb[(size_t)node_ids[n] * FIN + c];
    xq[(size_t)n * FIN + c] = bf16bits(v);
    xs[nl][c] = v;
  }
  __syncthreads();
  if (t < 64) {
    int nl2 = t >> 3, h = t & 7;
    int n2 = n0 + nl2;
    if (n2 < N_) {
      float sa = 0.f, sd = 0.f;
#pragma unroll
      for (int k = 0; k < FIN; ++k) {
        float x = xs[nl2][k];
        sa = fmaf(x, P[k * 8 + h], sa);
        sd = fmaf(x, P[256 + k * 8 + h], sd);
      }
      alsrc[(size_t)n2 * NH + h] = sa;
      aldst[(size_t)n2 * NH + h] = sd;
    }
  }
}

// ---- prep2: alsrc2/aldst2 = bf16(x1) @ P2 -----------------------------------
__global__ __launch_bounds__(256) void
prep2_kernel(const unsigned short* __restrict__ xq,
             const float* __restrict__ P,
             float* __restrict__ alsrc, float* __restrict__ aldst, int N_) {
  __shared__ float xs[8][33];
  int t = threadIdx.x, n0 = blockIdx.x * 8;
  int nl = t >> 5, c = t & 31;
  int n = n0 + nl;
  if (n < N_) xs[nl][c] = bf16tof(xq[(size_t)n * FIN + c]);
  __syncthreads();
  if (t < 64) {
    int nl2 = t >> 3, h = t & 7;
    int n2 = n0 + nl2;
    if (n2 < N_) {
      float sa = 0.f, sd = 0.f;
#pragma unroll
      for (int k = 0; k < FIN; ++k) {
        float x = xs[nl2][k];
        sa = fmaf(x, P[k * 8 + h], sa);
        sd = fmaf(x, P[256 + k * 8 + h], sd);
      }
      alsrc[(size_t)n2 * NH + h] = sa;
      aldst[(size_t)n2 * NH + h] = sd;
    }
  }
}

// ---- agg: softmax-weighted gather -> z (bf16, global) -----------------------
__global__ __launch_bounds__(256) void
agg_kernel(const int* __restrict__ rowptr, const int* __restrict__ srcs,
           const float* __restrict__ eattr, const float* __restrict__ Mg,
           const float* __restrict__ alsrc, const float* __restrict__ aldst,
           const unsigned short* __restrict__ xq,
           unsigned int* __restrict__ Zg, int N_) {
  __shared__ __align__(16) char smem[17920];
  unsigned int* xsu = (unsigned int*)smem;        // [CAP*16] packed bf16 (8 KB)
  float* wsf    = (float*)(smem + 8192);          // [CAP][8] (4 KB)
  float4* red4  = (float4*)smem;                  // [1024] combine pool (16 KB)
  float* Ms     = (float*)(smem + 16384);
  float* ald_s  = (float*)(smem + 16640);
  float* denred = (float*)(smem + 16768);
  float* den_s  = (float*)(smem + 17280);

  int t = threadIdx.x;
  int n0 = blockIdx.x * GROUP;
  int slot = t >> 6, l = t & 63, h = l >> 3, q = l & 7;

  int rp[GROUP + 1];
#pragma unroll
  for (int i = 0; i <= GROUP; ++i) {
    int nn = n0 + i;
    rp[i] = rowptr[(nn <= N_) ? nn : N_];
  }
  if (t < 64) Ms[t] = Mg[t];
  if (t < GROUP * NH) {
    int nn = n0 + (t >> 3);
    ald_s[t] = (nn < N_) ? aldst[(size_t)nn * NH + (t & 7)] : 0.f;
  }
  __syncthreads();

  float4 acc[GROUP];
  float dn[GROUP];
#pragma unroll
  for (int i = 0; i < GROUP; ++i) { acc[i] = make_float4(0.f, 0.f, 0.f, 0.f); dn[i] = 0.f; }

  int beg = rp[0], end = rp[GROUP];
  for (int cbeg = beg; cbeg < end; cbeg += CAP) {
    int clen = end - cbeg; if (clen > CAP) clen = CAP;

    int ntask = clen * 8;
    for (int idx = t; idx < ntask; idx += 256) {
      int e = idx >> 3, c4 = idx & 7;
      int s = srcs[cbeg + e];
      uint2 v = *(const uint2*)(xq + (size_t)s * FIN + c4 * 4);
      *(uint2*)&xsu[e * 16 + c4 * 2] = v;
    }
    {
      int e2 = t >> 1, half = t & 1;
      if (e2 < clen) {
        int j = cbeg + e2;
        int ii = 0;
        while (j >= rp[ii + 1]) ++ii;
        int sn = srcs[j];
        float4 eah = *(const float4*)(eattr + (size_t)j * NH + half * 4);
        float4 ash = *(const float4*)(alsrc + (size_t)sn * NH + half * 4);
        float eaf[4] = {eah.x, eah.y, eah.z, eah.w};
        float ea[8];
#pragma unroll
        for (int c = 0; c < 4; ++c) {
          float other = __shfl_xor(eaf[c], 1, 64);
          ea[half * 4 + c] = eaf[c];
          ea[(1 - half) * 4 + c] = other;
        }
        float asf[4] = {ash.x, ash.y, ash.z, ash.w};
        float o[4];
#pragma unroll
        for (int i4 = 0; i4 < 4; ++i4) {
          int hh = half * 4 + i4;
          float al = 0.f;
#pragma unroll
          for (int kk = 0; kk < NH; ++kk) al = fmaf(ea[kk], Ms[kk * NH + hh], al);
          float a = asf[i4] + ald_s[ii * NH + hh] + al;
          a = (a >= 0.f) ? a : 0.2f * a;
          o[i4] = __expf(a);
        }
        *(float4*)&wsf[e2 * 8 + half * 4] = make_float4(o[0], o[1], o[2], o[3]);
      }
    }
    __syncthreads();
#pragma unroll
    for (int i = 0; i < GROUP; ++i) {
      int lo = rp[i] > cbeg ? rp[i] - cbeg : 0;
      int hi = rp[i + 1] - cbeg; if (hi > clen) hi = clen;
      float4 a = acc[i];
      float d = dn[i];
#pragma unroll 2
      for (int le = lo + slot; le < hi; le += 4) {
        float w = wsf[le * 8 + h];
        uint2 u = *(const uint2*)&xsu[le * 16 + q * 2];
        a.x = fmaf(blo(u.x), w, a.x);
        a.y = fmaf(bhi(u.x), w, a.y);
        a.z = fmaf(blo(u.y), w, a.z);
        a.w = fmaf(bhi(u.y), w, a.w);
        d += w;
      }
      acc[i] = a; dn[i] = d;
    }
    __syncthreads();
  }

  if (q == 0) {
#pragma unroll
    for (int i = 0; i < GROUP; ++i) denred[slot * 32 + i * 8 + h] = dn[i];
  }
#pragma unroll
  for (int i = 0; i < GROUP; ++i) red4[i * 256 + t] = acc[i];
  __syncthreads();

  if (t < 32) {
    int i = t >> 3, hh = t & 7;
    float d = denred[i * 8 + hh] + denred[32 + i * 8 + hh] +
              denred[64 + i * 8 + hh] + denred[96 + i * 8 + hh];
    den_s[t] = 1.0f / (d + 1e-16f);
  }
  int i2 = t >> 6, l2 = t & 63;
  float4 r0 = red4[i2 * 256 + l2];
  float4 r1 = red4[i2 * 256 + 64 + l2];
  float4 r2 = red4[i2 * 256 + 128 + l2];
  float4 r3 = red4[i2 * 256 + 192 + l2];
  __syncthreads();
  float rden = den_s[i2 * 8 + (l2 >> 3)];
  float zx = (r0.x + r1.x + r2.x + r3.x) * rden;
  float zy = (r0.y + r1.y + r2.y + r3.y) * rden;
  float zz = (r0.z + r1.z + r2.z + r3.z) * rden;
  float zw = (r0.w + r1.w + r2.w + r3.w) * rden;
  int nn = n0 + i2;
  if (nn < N_) {
    unsigned int lo = (unsigned)bf16bits(zx) | ((unsigned)bf16bits(zy) << 16);
    unsigned int hi = (unsigned)bf16bits(zz) | ((unsigned)bf16bits(zw) << 16);
    uint2* zp = (uint2*)Zg;
    zp[(size_t)nn * 64 + l2] = make_uint2(lo, hi);
  }
}

// ---- epi: G = relu(Z @ W + b) via MFMA; x' = G @ Wlin + blin also via MFMA --
// 64-row tile, wave w owns rows w*16..w*16+15.
// A-frag: A[m=lane&15][k=quad*8+j]; C/D: row=quad*4+reg, col=lane&15.
template <int K2, bool LOGITS>
__global__ __launch_bounds__(256) void
epi_kernel(const unsigned int* __restrict__ Zg, const unsigned short* __restrict__ BpW,
           const unsigned short* __restrict__ BpL,
           const float* __restrict__ bvec, const float* __restrict__ blin,
           unsigned short* __restrict__ xqn, float* __restrict__ xoutf, int N_) {
  __shared__ __align__(16) unsigned short pool[64 * 264];  // 33.8 KB
  int t = threadIdx.x;
  int r0 = blockIdx.x * 64;

  // stage Z tile: 64 rows x 256 ch bf16 (row stride 264)
  for (int idx = t; idx < 64 * 64; idx += 256) {
    int row = idx >> 6, seg = idx & 63;
    uint2 v = (r0 + row < N_) ? ((const uint2*)Zg)[(size_t)(r0 + row) * 64 + seg]
                              : make_uint2(0u, 0u);
    *(uint2*)&pool[row * 264 + seg * 4] = v;
  }
  __syncthreads();

  int w = t >> 6, lane = t & 63;
  int quad = lane >> 4, n15 = lane & 15;

  // phase 1: G = Z @ W (blockdiag, per-head 32x32) -- 16 MFMAs
  const short8* bw = (const short8*)BpW;
  floatx4 acc0[8], acc1[8];
#pragma unroll
  for (int h = 0; h < 8; ++h) {
    floatx4 zi = {0.f, 0.f, 0.f, 0.f};
    short8 a = *(const short8*)&pool[(w * 16 + n15) * 264 + h * 32 + quad * 8];
    acc0[h] = __builtin_amdgcn_mfma_f32_16x16x32_bf16(a, bw[(h * 2 + 0) * 64 + lane], zi, 0, 0, 0);
    acc1[h] = __builtin_amdgcn_mfma_f32_16x16x32_bf16(a, bw[(h * 2 + 1) * 64 + lane], zi, 0, 0, 0);
  }
  __syncthreads();

  // write G row-major bf16 (wave w writes only its own rows)
#pragma unroll
  for (int h = 0; h < 8; ++h) {
#pragma unroll
    for (int nt = 0; nt < 2; ++nt) {
      floatx4 acc = nt ? acc1[h] : acc0[h];
      int col = h * 32 + nt * 16 + n15;
      float bb = bvec[col];
#pragma unroll
      for (int r = 0; r < 4; ++r) {
        float v = acc[r] + bb;
        pool[(w * 16 + quad * 4 + r) * 264 + col] = bf16bits(v > 0.f ? v : 0.f);
      }
    }
  }
  __syncthreads();

  // phase 2: out = G @ Wlin  -- 8*CT MFMAs per wave
  const short8* bl = (const short8*)BpL;
  constexpr int CT = (K2 > 16) ? 2 : 1;
  floatx4 oacc[CT];
#pragma unroll
  for (int ct = 0; ct < CT; ++ct) {
    floatx4 z = {0.f, 0.f, 0.f, 0.f};
#pragma unroll
    for (int kt = 0; kt < 8; ++kt) {
      short8 a = *(const short8*)&pool[(w * 16 + n15) * 264 + kt * 32 + quad * 8];
      z = __builtin_amdgcn_mfma_f32_16x16x32_bf16(a, bl[(kt * CT + ct) * 64 + lane], z, 0, 0, 0);
    }
    oacc[ct] = z;
  }

#pragma unroll
  for (int ct = 0; ct < CT; ++ct) {
    int col = ct * 16 + n15;
    float bb = (col < K2) ? blin[col] : 0.f;
#pragma unroll
    for (int r = 0; r < 4; ++r) {
      int grow = r0 + w * 16 + quad * 4 + r;
      if (grow < N_) {
        float v = oacc[ct][r] + bb;
        if (LOGITS) {
          xqn[(size_t)grow * 32 + col] = bf16bits(v);
        } else {
          if (col < K2) xoutf[(size_t)grow * K2 + col] = v;
        }
      }
    }
  }
}

// ---------------- classifier: sigmoid(sum(fu*fm)) ----------------------------
__global__ void clf_kernel(const int* __restrict__ eli, const float* __restrict__ ela,
                           const float* __restrict__ x2, const float* __restrict__ clfW,
                           const float* __restrict__ clfb, float* __restrict__ out, int L_) {
  int i = blockIdx.x * blockDim.x + threadIdx.x;
  if (i >= L_) return;
  int u = eli[i], m = eli[L_ + i];
  const float4* xup = (const float4*)(x2 + (size_t)u * NH);
  const float4* xmp = (const float4*)(x2 + (size_t)m * NH);
  const float4* eap = (const float4*)(ela + (size_t)i * NH);
  float4 xu0 = xup[0], xu1 = xup[1];
  float4 xm0 = xmp[0], xm1 = xmp[1];
  float4 el0 = eap[0], el1 = eap[1];
  float xu[NH] = {xu0.x, xu0.y, xu0.z, xu0.w, xu1.x, xu1.y, xu1.z, xu1.w};
  float xm[NH] = {xm0.x, xm0.y, xm0.z, xm0.w, xm1.x, xm1.y, xm1.z, xm1.w};
  float el[NH] = {el0.x, el0.y, el0.z, el0.w, el1.x, el1.y, el1.z, el1.w};
  float fu[NH];
#pragma unroll
  for (int kk = 0; kk < NH; ++kk) fu[kk] = clfb[kk];
#pragma unroll
  for (int j = 0; j < NH; ++j) {
#pragma unroll
    for (int kk = 0; kk < NH; ++kk) fu[kk] = fmaf(xu[j], clfW[j * NH + kk], fu[kk]);
  }
#pragma unroll
  for (int j = 0; j < NH; ++j) {
#pragma unroll
    for (int kk = 0; kk < NH; ++kk) fu[kk] = fmaf(el[j], clfW[(NH + j) * NH + kk], fu[kk]);
  }
  float dot = 0.f;
#pragma unroll
  for (int kk = 0; kk < NH; ++kk) dot += fu[kk] * xm[kk];
  out[i] = 1.f / (1.f + expf(-dot));
}

extern "C" void kernel_launch(void* const* d_in, const int* in_sizes, int n_in,
                              void* d_out, int out_size, void* d_ws, size_t ws_size,
                              hipStream_t stream) {
  const int* node_ids   = (const int*)d_in[0];
  const int* edge_index = (const int*)d_in[1];
  const int* eli        = (const int*)d_in[2];
  const float* edge_attr = (const float*)d_in[4];
  const float* ela       = (const float*)d_in[5];
  const float* emb       = (const float*)d_in[6];
  const float* W1     = (const float*)d_in[7];
  const float* a_src1 = (const float*)d_in[8];
  const float* a_dst1 = (const float*)d_in[9];
  const float* We1    = (const float*)d_in[10];
  const float* a_e1   = (const float*)d_in[11];
  const float* b1     = (const float*)d_in[12];
  const float* lin1W  = (const float*)d_in[13];
  const float* lin1b  = (const float*)d_in[14];
  const float* W2     = (const float*)d_in[15];
  const float* a_src2 = (const float*)d_in[16];
  const float* a_dst2 = (const float*)d_in[17];
  const float* We2    = (const float*)d_in[18];
  const float* a_e2   = (const float*)d_in[19];
  const float* b2     = (const float*)d_in[20];
  const float* lin5W  = (const float*)d_in[21];
  const float* lin5b  = (const float*)d_in[22];
  const float* clfW   = (const float*)d_in[23];
  const float* clfb   = (const float*)d_in[24];

  const int N_ = in_sizes[0];
  const int E_ = in_sizes[1] / 2;
  const int L_ = in_sizes[2] / 2;
  const int* src  = edge_index;
  const int* dstp = edge_index + E_;

  char* p = (char*)d_ws;
  auto carve = [&](size_t bytes) -> char* {
    char* r = p;
    p += (bytes + 255) & ~(size_t)255;
    return r;
  };
  unsigned short* xq1  = (unsigned short*)carve((size_t)N_ * FIN * 2);
  unsigned short* xq2  = (unsigned short*)carve((size_t)N_ * FIN * 2);
  unsigned int* Zbuf   = (unsigned int*)carve((size_t)N_ * HC * 2);
  float* eattr_s = (float*)carve((size_t)E_ * NH * 4);
  float* alsrc1  = (float*)carve((size_t)N_ * NH * 4);
  float* aldst1  = (float*)carve((size_t)N_ * NH * 4);
  float* alsrc2  = (float*)carve((size_t)N_ * NH * 4);
  float* aldst2  = (float*)carve((size_t)N_ * NH * 4);
  float* x2b     = (float*)carve((size_t)N_ * NH * 4);
  float* Mbuf    = (float*)carve(1152 * 4);
  unsigned short* Bp = (unsigned short*)carve(28672 * 2);
  int*   cnt     = (int*)carve((size_t)N_ * 4);
  int*   rowptr  = (int*)carve((size_t)(N_ + 1) * 4);
  int*   fill    = (int*)carve((size_t)N_ * 4);
  int*   stmp    = (int*)carve((size_t)N_ * 4);
  int*   bsum    = (int*)carve(1024 * 4);
  int*   srcs    = (int*)carve((size_t)E_ * 4);

  hipMemsetAsync(cnt, 0, (size_t)N_ * 4, stream);
  int eb = (E_ + 255) / 256;
  int nb = (N_ + 255) / 256;
  fold_kernel<<<1, 256, 0, stream>>>(We1, a_e1, We2, a_e2, W1, a_src1, a_dst1,
                                     W2, a_src2, a_dst2, lin1W, lin5W, Mbuf, Bp);
  count_kernel<<<eb, 256, 0, stream>>>(dstp, cnt, E_);
  scan_partial<<<nb, 256, 0, stream>>>(cnt, stmp, bsum, N_);
  scan_bsum<<<1, 1024, 0, stream>>>(bsum, nb);
  scan_final<<<nb, 256, 0, stream>>>(cnt, stmp, bsum, rowptr, fill, N_, E_);
  scatter_kernel<<<eb, 256, 0, stream>>>(src, dstp, fill, edge_attr, srcs, eattr_s, E_);
  prep1_kernel<<<(N_ + 7) / 8, 256, 0, stream>>>(emb, node_ids, Mbuf + 128,
                                                 xq1, alsrc1, aldst1, N_);

  int gb = (N_ + GROUP - 1) / GROUP;
  int ebk = (N_ + 63) / 64;
  // ---- layer 1 ----
  agg_kernel<<<gb, 256, 0, stream>>>(rowptr, srcs, eattr_s, Mbuf, alsrc1, aldst1,
                                     xq1, Zbuf, N_);
  epi_kernel<32, true><<<ebk, 256, 0, stream>>>(Zbuf, Bp, Bp + 16384, b1, lin1b,
                                                xq2, nullptr, N_);
  prep2_kernel<<<(N_ + 7) / 8, 256, 0, stream>>>(xq2, Mbuf + 640, alsrc2, aldst2, N_);

  // ---- layer 2 ----
  agg_kernel<<<gb, 256, 0, stream>>>(rowptr, srcs, eattr_s, Mbuf + 64, alsrc2, aldst2,
                                     xq2, Zbuf, N_);
  epi_kernel<8, false><<<ebk, 256, 0, stream>>>(Zbuf, Bp + 8192, Bp + 24576, b2, lin5b,
                                                nullptr, x2b, N_);

  // ---- classifier ----
  clf_kernel<<<(L_ + 255) / 256, 256, 0, stream>>>(eli, ela, x2b, clfW, clfb,
                                                   (float*)d_out, L_);
}